// Round 1
// baseline (778.373 us; speedup 1.0000x reference)
//
#include <hip/hip_runtime.h>
#include <math.h>

#define NB 8
#define CHN 256
#define HWD 96
#define PIXN (HWD*HWD)        // 9216 pixels per image
#define TOTPIX (NB*PIXN)      // 73728
#define VCN 512
#define OHW 30
#define LPP (OHW*OHW)         // 900 patches per image
#define NPATCH (NB*LPP)       // 7200
#define INPD 320
#define HID 768

// ---------------- norms ----------------
__global__ void wnorm_k(const float* __restrict__ cw, float* __restrict__ invw){
  int v = blockIdx.x*256 + threadIdx.x;
  if (v >= VCN) return;
  const float* r = cw + (size_t)v*CHN;
  float s = 0.f;
  #pragma unroll 4
  for (int c=0;c<CHN;c++){ float t=r[c]; s = fmaf(t,t,s); }
  invw[v] = 1.0f/sqrtf(s);
}

__global__ void pixnorm_k(const float* __restrict__ x, float* __restrict__ invpix){
  int p = blockIdx.x*256 + threadIdx.x;
  if (p >= TOTPIX) return;
  int n = p / PIXN, pl = p % PIXN;
  const float* xp = x + (size_t)n*CHN*PIXN + pl;
  float s = 0.f;
  #pragma unroll 4
  for (int c=0;c<CHN;c++){ float t = xp[(size_t)c*PIXN]; s = fmaf(t,t,s); }
  invpix[p] = 1.0f/sqrtf(s);
}

// ---------------- per-pixel cosine-sim GEMM + per-tile argmax ----------------
// z[p][v] = sum_c x[n,c,py,px]*cw[v,c] * invpix[p] * invw[v]
// Each block: 64 pixels x 64 filters; writes per-pixel (max, argmax-v) candidate
// for its v-tile. 8 candidates per pixel get reduced in select_k.
__global__ __launch_bounds__(256) void gemm_z_k(
    const float* __restrict__ x, const float* __restrict__ cw,
    const float* __restrict__ invpix, const float* __restrict__ invw,
    float* __restrict__ mcand, int* __restrict__ vcand){
  __shared__ __align__(16) float As[16][68];
  __shared__ __align__(16) float Bs[16][68];
  __shared__ float rv[64][17];
  __shared__ int   ri[64][17];
  const int t = threadIdx.x;
  const int m0 = blockIdx.x * 64;
  const int img = m0 / PIXN;
  const int pl0 = m0 % PIXN;
  const int v0 = blockIdx.y * 64;
  const float* xb = x + (size_t)img*CHN*PIXN + pl0;
  const int tm = t & 15, tn = t >> 4;
  const int am = t & 63, ak = (t >> 6) * 4;
  const int bvr = t >> 2, bcc = (t & 3) * 4;
  float acc[4][4] = {};
  for (int k0 = 0; k0 < CHN; k0 += 16){
    float a0 = xb[(size_t)(k0+ak+0)*PIXN + am];
    float a1 = xb[(size_t)(k0+ak+1)*PIXN + am];
    float a2 = xb[(size_t)(k0+ak+2)*PIXN + am];
    float a3 = xb[(size_t)(k0+ak+3)*PIXN + am];
    const float4 b4 = *(const float4*)&cw[(size_t)(v0+bvr)*CHN + k0 + bcc];
    __syncthreads();
    As[ak+0][am]=a0; As[ak+1][am]=a1; As[ak+2][am]=a2; As[ak+3][am]=a3;
    Bs[bcc+0][bvr]=b4.x; Bs[bcc+1][bvr]=b4.y; Bs[bcc+2][bvr]=b4.z; Bs[bcc+3][bvr]=b4.w;
    __syncthreads();
    #pragma unroll
    for (int k=0;k<16;k++){
      const float4 a = *(const float4*)&As[k][tm*4];
      const float4 b = *(const float4*)&Bs[k][tn*4];
      acc[0][0]=fmaf(a.x,b.x,acc[0][0]); acc[0][1]=fmaf(a.x,b.y,acc[0][1]);
      acc[0][2]=fmaf(a.x,b.z,acc[0][2]); acc[0][3]=fmaf(a.x,b.w,acc[0][3]);
      acc[1][0]=fmaf(a.y,b.x,acc[1][0]); acc[1][1]=fmaf(a.y,b.y,acc[1][1]);
      acc[1][2]=fmaf(a.y,b.z,acc[1][2]); acc[1][3]=fmaf(a.y,b.w,acc[1][3]);
      acc[2][0]=fmaf(a.z,b.x,acc[2][0]); acc[2][1]=fmaf(a.z,b.y,acc[2][1]);
      acc[2][2]=fmaf(a.z,b.z,acc[2][2]); acc[2][3]=fmaf(a.z,b.w,acc[2][3]);
      acc[3][0]=fmaf(a.w,b.x,acc[3][0]); acc[3][1]=fmaf(a.w,b.y,acc[3][1]);
      acc[3][2]=fmaf(a.w,b.z,acc[3][2]); acc[3][3]=fmaf(a.w,b.w,acc[3][3]);
    }
  }
  float iwv[4];
  #pragma unroll
  for (int j=0;j<4;j++) iwv[j] = invw[v0 + tn*4 + j];
  #pragma unroll
  for (int i=0;i<4;i++){
    const int pix = m0 + tm*4 + i;
    const float ip = invpix[pix];
    float bz = -1e30f; int bvi = 0;
    #pragma unroll
    for (int j=0;j<4;j++){
      float z = acc[i][j]*ip*iwv[j];
      if (z > bz){ bz = z; bvi = v0 + tn*4 + j; }   // ascending v: strict > keeps lowest v on tie
    }
    rv[tm*4+i][tn] = bz; ri[tm*4+i][tn] = bvi;
  }
  __syncthreads();
  if (t < 64){
    float best = rv[t][0]; int bi = ri[t][0];
    #pragma unroll
    for (int s=1;s<16;s++){
      float v2 = rv[t][s]; int i2 = ri[t][s];
      if (v2 > best || (v2 == best && i2 < bi)){ best=v2; bi=i2; }
    }
    mcand[(size_t)(m0+t)*8 + blockIdx.y] = best;
    vcand[(size_t)(m0+t)*8 + blockIdx.y] = bi;
  }
}

// ---------------- per-patch selection, builds MLP input (7200 x 320) ----------------
__global__ void select_k(const float* __restrict__ x, const float* __restrict__ cw,
    const float* __restrict__ invpix, const float* __restrict__ invw,
    const float* __restrict__ mcand, const int* __restrict__ vcand,
    float* __restrict__ inp){
  const int q = blockIdx.x;      // patch id
  const int lane = threadIdx.x;  // 0..63 = window position ky*8+kx
  const int n = q / LPP, l = q % LPP;
  const int oy = l / OHW, ox = l % OHW;
  const int pl = (oy*3 + (lane >> 3))*HWD + (ox*3 + (lane & 7));
  const int p = n*PIXN + pl;
  // reduce the 8 v-tile candidates for this lane's pixel
  float best = -1e30f; int bv = 0;
  #pragma unroll
  for (int s=0;s<8;s++){
    float v2 = mcand[(size_t)p*8 + s];
    int i2 = vcand[(size_t)p*8 + s];
    if (v2 > best || (v2 == best && i2 < bv)){ best = v2; bv = i2; }
  }
  // wave argmax across 64 window positions; tie-break = reference flat idx v*64+pos
  float val = best;
  int flat = bv*64 + lane;
  #pragma unroll
  for (int off=32; off>0; off>>=1){
    float ov = __shfl_xor(val, off);
    int of = __shfl_xor(flat, off);
    if (ov > val || (ov == val && of < flat)){ val = ov; flat = of; }
  }
  const int mch = flat >> 6;
  const int pos = flat & 63;
  const float ms = val;
  // sim_map: recompute cosine sim of this lane's pixel vs winning filter
  const float* xp = x + (size_t)n*CHN*PIXN + pl;
  const float* wr = cw + (size_t)mch*CHN;
  float d0=0.f,d1=0.f,d2=0.f,d3=0.f;
  for (int c=0;c<CHN;c+=4){
    d0 = fmaf(xp[(size_t)(c+0)*PIXN], wr[c+0], d0);
    d1 = fmaf(xp[(size_t)(c+1)*PIXN], wr[c+1], d1);
    d2 = fmaf(xp[(size_t)(c+2)*PIXN], wr[c+2], d2);
    d3 = fmaf(xp[(size_t)(c+3)*PIXN], wr[c+3], d3);
  }
  float sim = ((d0+d1)+(d2+d3)) * invpix[p] * invw[mch];
  inp[(size_t)q*INPD + 256 + lane] = sim;
  // integ: x at winning window pixel blended with winning filter vector
  const int wpl = (oy*3 + (pos>>3))*HWD + (ox*3 + (pos&7));
  const float* xw = x + (size_t)n*CHN*PIXN + wpl;
  const float om = 1.0f - ms;
  #pragma unroll
  for (int tt=0;tt<4;tt++){
    int c = lane + 64*tt;
    float act = xw[(size_t)c*PIXN];
    inp[(size_t)q*INPD + c] = fmaf(act, ms, wr[c]*om);
  }
}

// ---------------- MLP GEMMs: C = act(A @ B^T + bias) ----------------
// A (MxK) row-major, B (NxK) row-major. EPI 1 = leaky relu, 2 = tanh.
template<int EPI>
__global__ __launch_bounds__(256) void gemm_rm_k(
    const float* __restrict__ A, const float* __restrict__ B,
    const float* __restrict__ bias, float* __restrict__ C,
    int M, int N, int K){
  __shared__ __align__(16) float As[16][68];
  __shared__ __align__(16) float Bs[16][68];
  const int t = threadIdx.x;
  const int m0 = blockIdx.x*64, n0 = blockIdx.y*64;
  const int tm = t & 15, tn = t >> 4;
  const int ar = t >> 2, ac = (t & 3)*4;
  float acc[4][4] = {};
  for (int k0=0;k0<K;k0+=16){
    float4 av = make_float4(0.f,0.f,0.f,0.f);
    if (m0 + ar < M) av = *(const float4*)&A[(size_t)(m0+ar)*K + k0 + ac];
    const float4 b4 = *(const float4*)&B[(size_t)(n0+ar)*K + k0 + ac];
    __syncthreads();
    As[ac+0][ar]=av.x; As[ac+1][ar]=av.y; As[ac+2][ar]=av.z; As[ac+3][ar]=av.w;
    Bs[ac+0][ar]=b4.x; Bs[ac+1][ar]=b4.y; Bs[ac+2][ar]=b4.z; Bs[ac+3][ar]=b4.w;
    __syncthreads();
    #pragma unroll
    for (int k=0;k<16;k++){
      const float4 a = *(const float4*)&As[k][tm*4];
      const float4 b = *(const float4*)&Bs[k][tn*4];
      acc[0][0]=fmaf(a.x,b.x,acc[0][0]); acc[0][1]=fmaf(a.x,b.y,acc[0][1]);
      acc[0][2]=fmaf(a.x,b.z,acc[0][2]); acc[0][3]=fmaf(a.x,b.w,acc[0][3]);
      acc[1][0]=fmaf(a.y,b.x,acc[1][0]); acc[1][1]=fmaf(a.y,b.y,acc[1][1]);
      acc[1][2]=fmaf(a.y,b.z,acc[1][2]); acc[1][3]=fmaf(a.y,b.w,acc[1][3]);
      acc[2][0]=fmaf(a.z,b.x,acc[2][0]); acc[2][1]=fmaf(a.z,b.y,acc[2][1]);
      acc[2][2]=fmaf(a.z,b.z,acc[2][2]); acc[2][3]=fmaf(a.z,b.w,acc[2][3]);
      acc[3][0]=fmaf(a.w,b.x,acc[3][0]); acc[3][1]=fmaf(a.w,b.y,acc[3][1]);
      acc[3][2]=fmaf(a.w,b.z,acc[3][2]); acc[3][3]=fmaf(a.w,b.w,acc[3][3]);
    }
  }
  float bb[4];
  #pragma unroll
  for (int j=0;j<4;j++) bb[j] = bias[n0 + tn*4 + j];
  #pragma unroll
  for (int i=0;i<4;i++){
    const int gm = m0 + tm*4 + i;
    if (gm < M){
      float r[4];
      #pragma unroll
      for (int j=0;j<4;j++){
        float v = acc[i][j] + bb[j];
        if (EPI == 1) v = v > 0.f ? v : 0.2f*v;
        else          v = tanhf(v);
        r[j] = v;
      }
      float4 o = make_float4(r[0],r[1],r[2],r[3]);
      *(float4*)&C[(size_t)gm*N + n0 + tn*4] = o;
    }
  }
}

extern "C" void kernel_launch(void* const* d_in, const int* in_sizes, int n_in,
                              void* d_out, int out_size, void* d_ws, size_t ws_size,
                              hipStream_t stream){
  const float* x  = (const float*)d_in[0];
  const float* cw = (const float*)d_in[1];
  const float* W1 = (const float*)d_in[2];
  const float* b1 = (const float*)d_in[3];
  const float* W2 = (const float*)d_in[4];
  const float* b2 = (const float*)d_in[5];
  float* out = (float*)d_out;
  float* ws = (float*)d_ws;
  float* invpix = ws;                                  // 73728
  float* invw   = invpix + TOTPIX;                     // 512
  float* mcand  = invw + VCN;                          // 73728*8
  int*   vcand  = (int*)(mcand + (size_t)TOTPIX*8);    // 73728*8
  float* inp    = (float*)(vcand + (size_t)TOTPIX*8);  // 7200*320
  float* h1     = inp + (size_t)NPATCH*INPD;           // 7200*768
  // total ws use ~36.3 MB

  wnorm_k<<<2,256,0,stream>>>(cw, invw);
  pixnorm_k<<<TOTPIX/256,256,0,stream>>>(x, invpix);
  gemm_z_k<<<dim3(TOTPIX/64, VCN/64),256,0,stream>>>(x, cw, invpix, invw, mcand, vcand);
  select_k<<<NPATCH,64,0,stream>>>(x, cw, invpix, invw, mcand, vcand, inp);
  gemm_rm_k<1><<<dim3((NPATCH+63)/64, HID/64),256,0,stream>>>(inp, W1, b1, h1, NPATCH, HID, INPD);
  gemm_rm_k<2><<<dim3((NPATCH+63)/64, CHN/64),256,0,stream>>>(h1, W2, b2, out, NPATCH, CHN, HID);
}

// Round 2
// 731.305 us; speedup vs baseline: 1.0644x; 1.0644x over previous
//
#include <hip/hip_runtime.h>
#include <math.h>

#define NB 8
#define CHN 256
#define HWD 96
#define PIXN (HWD*HWD)        // 9216 pixels per image
#define TOTPIX (NB*PIXN)      // 73728
#define VCN 512
#define OHW 30
#define LPP (OHW*OHW)         // 900 patches per image
#define NPATCH (NB*LPP)       // 7200
#define INPD 320
#define HID 768

// ---------------- norms ----------------
__global__ void wnorm_k(const float* __restrict__ cw, float* __restrict__ invw){
  int v = blockIdx.x*256 + threadIdx.x;
  if (v >= VCN) return;
  const float* r = cw + (size_t)v*CHN;
  float s = 0.f;
  #pragma unroll 4
  for (int c=0;c<CHN;c++){ float t=r[c]; s = fmaf(t,t,s); }
  invw[v] = 1.0f/sqrtf(s);
}

__global__ void pixnorm_k(const float* __restrict__ x, float* __restrict__ invpix){
  int p = blockIdx.x*256 + threadIdx.x;
  if (p >= TOTPIX) return;
  int n = p / PIXN, pl = p % PIXN;
  const float* xp = x + (size_t)n*CHN*PIXN + pl;
  float s = 0.f;
  #pragma unroll 4
  for (int c=0;c<CHN;c++){ float t = xp[(size_t)c*PIXN]; s = fmaf(t,t,s); }
  invpix[p] = 1.0f/sqrtf(s);
}

// ---------------- per-pixel cosine-sim GEMM + per-tile argmax ----------------
// 128x128 block tile, 8x8 per thread (1.0 B LDS / MAC -> LDS port no longer 2x
// oversubscribed as with the old 4x4 tile).
// blockIdx.x = v-tile (4), blockIdx.y = m-tile (576): the 4 v-tiles of one
// m-tile are dispatch-adjacent -> x tile read once through L2/LLC.
__global__ __launch_bounds__(256) void gemm_z_k(
    const float* __restrict__ x, const float* __restrict__ cw,
    const float* __restrict__ invpix, const float* __restrict__ invw,
    float* __restrict__ mcand, int* __restrict__ vcand){
  __shared__ __align__(16) char smem[17408];
  float (*As)[132] = (float(*)[132])smem;                 // [16][132] 8448 B
  float (*Bs)[132] = (float(*)[132])(smem + 8448);        // [16][132] 8448 B
  const int t = threadIdx.x;
  const int m0 = blockIdx.y * 128;
  const int v0 = blockIdx.x * 128;
  const int img = m0 / PIXN;
  const int pl0 = m0 % PIXN;
  const float* xb = x + (size_t)img*CHN*PIXN + pl0;
  const int tm = t & 15, tn = t >> 4;
  // A staging: k_a = t>>4 (16 rows), m_a = (t&15)*8 -> 2 float4, b128 LDS writes
  const int k_a = t >> 4, m_a = (t & 15) * 8;
  // B staging: v_b = t>>1 (128 rows), k_b = (t&1)*8 -> transpose scatter
  const int v_b = t >> 1, k_b = (t & 1) * 8;
  float acc[8][8] = {};
  for (int k0 = 0; k0 < CHN; k0 += 16){
    const float4 a4l = *(const float4*)&xb[(size_t)(k0+k_a)*PIXN + m_a];
    const float4 a4h = *(const float4*)&xb[(size_t)(k0+k_a)*PIXN + m_a + 4];
    float bv[8];
    *(float4*)&bv[0] = *(const float4*)&cw[(size_t)(v0+v_b)*CHN + k0 + k_b];
    *(float4*)&bv[4] = *(const float4*)&cw[(size_t)(v0+v_b)*CHN + k0 + k_b + 4];
    __syncthreads();
    *(float4*)&As[k_a][m_a]     = a4l;
    *(float4*)&As[k_a][m_a + 4] = a4h;
    #pragma unroll
    for (int j=0;j<8;j++) Bs[k_b+j][v_b] = bv[j];
    __syncthreads();
    #pragma unroll
    for (int k=0;k<16;k++){
      float ar[8], br[8];
      *(float4*)&ar[0] = *(const float4*)&As[k][tm*4];
      *(float4*)&ar[4] = *(const float4*)&As[k][64 + tm*4];
      *(float4*)&br[0] = *(const float4*)&Bs[k][tn*4];
      *(float4*)&br[4] = *(const float4*)&Bs[k][64 + tn*4];
      #pragma unroll
      for (int i=0;i<8;i++)
        #pragma unroll
        for (int j=0;j<8;j++)
          acc[i][j] = fmaf(ar[i], br[j], acc[i][j]);
    }
  }
  // epilogue: per-pixel argmax over this block's 128 v values
  float iwv[8];
  #pragma unroll
  for (int jb=0;jb<2;jb++)
    #pragma unroll
    for (int j=0;j<4;j++) iwv[jb*4+j] = invw[v0 + jb*64 + tn*4 + j];
  __syncthreads();                          // done reading As/Bs; reuse smem
  float (*rv)[17] = (float(*)[17])smem;     // [128][17] 8704 B
  int   (*ri)[17] = (int(*)[17])(smem + 8704);
  #pragma unroll
  for (int ib=0;ib<2;ib++){
    #pragma unroll
    for (int i=0;i<4;i++){
      const int r = ib*64 + tm*4 + i;
      const float ip = invpix[m0 + r];
      float bz = -1e30f; int bvi = 0;
      #pragma unroll
      for (int jj=0;jj<8;jj++){           // jj ascending => ascending v
        const int vv = v0 + (jj<4 ? tn*4+jj : 64 + tn*4 + (jj-4));
        float z = acc[ib*4+i][jj]*ip*iwv[jj];
        if (z > bz){ bz = z; bvi = vv; }  // strict > keeps lowest v on tie
      }
      rv[r][tn] = bz; ri[r][tn] = bvi;
    }
  }
  __syncthreads();
  if (t < 128){
    float best = rv[t][0]; int bi = ri[t][0];
    #pragma unroll
    for (int s=1;s<16;s++){
      float v2 = rv[t][s]; int i2 = ri[t][s];
      if (v2 > best || (v2 == best && i2 < bi)){ best=v2; bi=i2; }
    }
    mcand[(size_t)(m0+t)*4 + blockIdx.x] = best;
    vcand[(size_t)(m0+t)*4 + blockIdx.x] = bi;
  }
}

// ---------------- per-patch selection, builds MLP input (7200 x 320) ----------------
__global__ void select_k(const float* __restrict__ x, const float* __restrict__ cw,
    const float* __restrict__ invpix, const float* __restrict__ invw,
    const float* __restrict__ mcand, const int* __restrict__ vcand,
    float* __restrict__ inp){
  const int q = blockIdx.x;      // patch id
  const int lane = threadIdx.x;  // 0..63 = window position ky*8+kx
  const int n = q / LPP, l = q % LPP;
  const int oy = l / OHW, ox = l % OHW;
  const int pl = (oy*3 + (lane >> 3))*HWD + (ox*3 + (lane & 7));
  const int p = n*PIXN + pl;
  // reduce the 4 v-tile candidates for this lane's pixel
  float best = -1e30f; int bv = 0;
  #pragma unroll
  for (int s=0;s<4;s++){
    float v2 = mcand[(size_t)p*4 + s];
    int i2 = vcand[(size_t)p*4 + s];
    if (v2 > best || (v2 == best && i2 < bv)){ best = v2; bv = i2; }
  }
  // wave argmax across 64 window positions; tie-break = reference flat idx v*64+pos
  float val = best;
  int flat = bv*64 + lane;
  #pragma unroll
  for (int off=32; off>0; off>>=1){
    float ov = __shfl_xor(val, off);
    int of = __shfl_xor(flat, off);
    if (ov > val || (ov == val && of < flat)){ val = ov; flat = of; }
  }
  const int mch = flat >> 6;
  const int pos = flat & 63;
  const float ms = val;
  // sim_map: recompute cosine sim of this lane's pixel vs winning filter
  const float* xp = x + (size_t)n*CHN*PIXN + pl;
  const float* wr = cw + (size_t)mch*CHN;
  float d0=0.f,d1=0.f,d2=0.f,d3=0.f;
  for (int c=0;c<CHN;c+=4){
    d0 = fmaf(xp[(size_t)(c+0)*PIXN], wr[c+0], d0);
    d1 = fmaf(xp[(size_t)(c+1)*PIXN], wr[c+1], d1);
    d2 = fmaf(xp[(size_t)(c+2)*PIXN], wr[c+2], d2);
    d3 = fmaf(xp[(size_t)(c+3)*PIXN], wr[c+3], d3);
  }
  float sim = ((d0+d1)+(d2+d3)) * invpix[p] * invw[mch];
  inp[(size_t)q*INPD + 256 + lane] = sim;
  // integ: x at winning window pixel blended with winning filter vector
  const int wpl = (oy*3 + (pos>>3))*HWD + (ox*3 + (pos&7));
  const float* xw = x + (size_t)n*CHN*PIXN + wpl;
  const float om = 1.0f - ms;
  #pragma unroll
  for (int tt=0;tt<4;tt++){
    int c = lane + 64*tt;
    float act = xw[(size_t)c*PIXN];
    inp[(size_t)q*INPD + c] = fmaf(act, ms, wr[c]*om);
  }
}

// ---------------- MLP GEMMs: C = act(A @ B^T + bias) ----------------
// A (MxK) row-major, B (NxK) row-major, 128x128 tile, 8x8/thread.
// N must be a multiple of 128 (holds: 768, 256); M guarded.
// EPI 1 = leaky relu, 2 = tanh.
template<int EPI>
__global__ __launch_bounds__(256) void gemm_rm_k(
    const float* __restrict__ A, const float* __restrict__ B,
    const float* __restrict__ bias, float* __restrict__ C,
    int M, int N, int K){
  __shared__ __align__(16) char smem[16896];
  float (*As)[132] = (float(*)[132])smem;
  float (*Bs)[132] = (float(*)[132])(smem + 8448);
  const int t = threadIdx.x;
  const int n0 = blockIdx.x * 128;
  const int m0 = blockIdx.y * 128;
  const int tm = t & 15, tn = t >> 4;
  const int r_s = t >> 1, k_s = (t & 1) * 8;   // staging: row t>>1, k-chunk (t&1)*8
  float acc[8][8] = {};
  for (int k0 = 0; k0 < K; k0 += 16){
    float av[8] = {};
    if (m0 + r_s < M){
      *(float4*)&av[0] = *(const float4*)&A[(size_t)(m0+r_s)*K + k0 + k_s];
      *(float4*)&av[4] = *(const float4*)&A[(size_t)(m0+r_s)*K + k0 + k_s + 4];
    }
    float bv[8];
    *(float4*)&bv[0] = *(const float4*)&B[(size_t)(n0+r_s)*K + k0 + k_s];
    *(float4*)&bv[4] = *(const float4*)&B[(size_t)(n0+r_s)*K + k0 + k_s + 4];
    __syncthreads();
    #pragma unroll
    for (int j=0;j<8;j++){ As[k_s+j][r_s] = av[j]; Bs[k_s+j][r_s] = bv[j]; }
    __syncthreads();
    #pragma unroll
    for (int k=0;k<16;k++){
      float ar[8], br[8];
      *(float4*)&ar[0] = *(const float4*)&As[k][tm*4];
      *(float4*)&ar[4] = *(const float4*)&As[k][64 + tm*4];
      *(float4*)&br[0] = *(const float4*)&Bs[k][tn*4];
      *(float4*)&br[4] = *(const float4*)&Bs[k][64 + tn*4];
      #pragma unroll
      for (int i=0;i<8;i++)
        #pragma unroll
        for (int j=0;j<8;j++)
          acc[i][j] = fmaf(ar[i], br[j], acc[i][j]);
    }
  }
  float bb[8];
  #pragma unroll
  for (int jb=0;jb<2;jb++)
    #pragma unroll
    for (int j=0;j<4;j++) bb[jb*4+j] = bias[n0 + jb*64 + tn*4 + j];
  #pragma unroll
  for (int ib=0;ib<2;ib++){
    #pragma unroll
    for (int i=0;i<4;i++){
      const int gm = m0 + ib*64 + tm*4 + i;
      if (gm < M){
        #pragma unroll
        for (int jb=0;jb<2;jb++){
          float r[4];
          #pragma unroll
          for (int j=0;j<4;j++){
            float v = acc[ib*4+i][jb*4+j] + bb[jb*4+j];
            if (EPI == 1) v = v > 0.f ? v : 0.2f*v;
            else          v = tanhf(v);
            r[j] = v;
          }
          *(float4*)&C[(size_t)gm*N + n0 + jb*64 + tn*4] = make_float4(r[0],r[1],r[2],r[3]);
        }
      }
    }
  }
}

extern "C" void kernel_launch(void* const* d_in, const int* in_sizes, int n_in,
                              void* d_out, int out_size, void* d_ws, size_t ws_size,
                              hipStream_t stream){
  const float* x  = (const float*)d_in[0];
  const float* cw = (const float*)d_in[1];
  const float* W1 = (const float*)d_in[2];
  const float* b1 = (const float*)d_in[3];
  const float* W2 = (const float*)d_in[4];
  const float* b2 = (const float*)d_in[5];
  float* out = (float*)d_out;
  float* ws = (float*)d_ws;
  float* invpix = ws;                                  // 73728
  float* invw   = invpix + TOTPIX;                     // 512
  float* mcand  = invw + VCN;                          // 73728*4
  int*   vcand  = (int*)(mcand + (size_t)TOTPIX*4);    // 73728*4
  float* inp    = (float*)(vcand + (size_t)TOTPIX*4);  // 7200*320
  float* h1     = inp + (size_t)NPATCH*INPD;           // 7200*768
  // total ws use ~33 MB

  wnorm_k<<<2,256,0,stream>>>(cw, invw);
  pixnorm_k<<<TOTPIX/256,256,0,stream>>>(x, invpix);
  gemm_z_k<<<dim3(VCN/128, TOTPIX/128),256,0,stream>>>(x, cw, invpix, invw, mcand, vcand);
  select_k<<<NPATCH,64,0,stream>>>(x, cw, invpix, invw, mcand, vcand, inp);
  gemm_rm_k<1><<<dim3(HID/128, (NPATCH+127)/128),256,0,stream>>>(inp, W1, b1, h1, NPATCH, HID, INPD);
  gemm_rm_k<2><<<dim3(CHN/128, (NPATCH+127)/128),256,0,stream>>>(h1, W2, b2, out, NPATCH, CHN, HID);
}